// Round 8
// baseline (352.159 us; speedup 1.0000x reference)
//
#include <hip/hip_runtime.h>
#include <hip/hip_bf16.h>
#include <stdint.h>

// out[b,o] = sum_{k,i} hyp[b,k]*h[b,i]*W2[k,i*256+o] + sum_i h[b,i]*b2[i*256+o] + bias[o]
// GEMM A[4096 x 131328] * B[131328 x 256], A = diag(hyp_k)*H per k-group — all FP16.
// A-frag scaled in regs (v_pk_mul_f16, row is lane-local), MFMA accumulates via C operand.
// B = W2 flat f16, pre-packed transposed+swizzled; 3-deep 16KB LDS ring via global_load_lds,
// counted vmcnt(2), ONE raw s_barrier/iter, setprio on MFMA cluster.
// BM=128, BN=128 (nt split) -> 64KB LDS/block -> 2 blocks/CU (16 waves/CU) for
// cross-block bubble-filling (the m114 mechanism).
// ws: [0,8.4M) hypT fp32 [513][4096] (row 512 = ones, folds b2); [9M,+2M) h f16; [12M,+67.2M) packed B.

typedef _Float16 f16x8 __attribute__((ext_vector_type(8)));
typedef _Float16 f16x4 __attribute__((ext_vector_type(4)));
typedef float    f32x4 __attribute__((ext_vector_type(4)));

#define KTILES     2052
#define TILE_BYTES 32768          // 256 cols * 64 k * 2B
#define HB_OFF     (9u*1024u*1024u)
#define BP_OFF     (12u*1024u*1024u)

// ---------------- out = bias ----------------
__global__ void k_init_out(const float* __restrict__ bias, float* __restrict__ out) {
    int idx = blockIdx.x * 256 + threadIdx.x;
    out[idx] = bias[idx & 255];
}

// ---------------- h fp32 -> f16 ----------------
__global__ void k_hcast(const float* __restrict__ h, _Float16* __restrict__ hb) {
    int i = (blockIdx.x * 256 + threadIdx.x) * 8;    // grid 512 x 256
    f32x4 a = *(const f32x4*)(h + i);
    f32x4 b = *(const f32x4*)(h + i + 4);
    f16x8 v;
    v[0] = (_Float16)a[0]; v[1] = (_Float16)a[1]; v[2] = (_Float16)a[2]; v[3] = (_Float16)a[3];
    v[4] = (_Float16)b[0]; v[5] = (_Float16)b[1]; v[6] = (_Float16)b[2]; v[7] = (_Float16)b[3];
    *(f16x8*)(hb + i) = v;
}

// ---------------- hypT[k][b] = relu(z@W1+b1)^T; row 512 = 1.0 ----------------
__global__ void k_hypT(const float* __restrict__ z, const float* __restrict__ W1,
                       const float* __restrict__ b1, float* __restrict__ hypT) {
    int blk = blockIdx.x;
    int t   = threadIdx.x;                       // 512 threads; t == k
    if (blk == 128) {                            // ones row (b2 scale)
#pragma unroll
        for (int r = 0; r < 8; ++r) hypT[(size_t)512*4096 + r*512 + t] = 1.0f;
        return;
    }
    __shared__ float zs[32][128];
    int b0 = blk * 32;
#pragma unroll
    for (int u = 0; u < 8; ++u) {
        int idx = u * 512 + t;
        zs[idx >> 7][idx & 127] = z[b0 * 128 + idx];
    }
    __syncthreads();
    float acc[32];
    float bk = b1[t];
#pragma unroll
    for (int b = 0; b < 32; ++b) acc[b] = bk;
    for (int c = 0; c < 128; ++c) {
        float w = W1[c * 512 + t];
#pragma unroll
        for (int b = 0; b < 32; ++b) acc[b] = fmaf(zs[b][c], w, acc[b]);
    }
    float* dst = hypT + (size_t)t * 4096 + b0;
#pragma unroll
    for (int v = 0; v < 8; ++v) {
        f32x4 o;
#pragma unroll
        for (int q = 0; q < 4; ++q) {
            float a = acc[v * 4 + q];
            o[q] = a > 0.f ? a : 0.f;
        }
        *(f32x4*)(dst + v * 4) = o;
    }
}

// ---------------- pack W2 (+b2) -> f16 transposed+swizzled tiles ----------------
// dst element (kk,o) at byte (o*128 + kk*2) ^ ((o&7)<<4); build in LDS, stream out 16B.
__global__ void k_pack(const float* __restrict__ W2, const float* __restrict__ b2,
                       _Float16* __restrict__ Bp) {
    __shared__ char tile[TILE_BYTES];
    int t   = blockIdx.x;
    int tid = threadIdx.x;        // 256
    long row0 = (long)t * 64;
    const float* src = (t < 2048) ? (W2 + row0 * 256) : (b2 + (row0 - 131072) * 256);
#pragma unroll
    for (int u = 0; u < 16; ++u) {
        int f = (u * 256 + tid) * 4;              // flat fp32 idx, coalesced
        f32x4 v = *(const f32x4*)(src + f);
        int kk = f >> 8;
        int o0 = f & 255;
#pragma unroll
        for (int j = 0; j < 4; ++j) {
            int o = o0 + j;
            int addr = (o * 128 + kk * 2) ^ ((o & 7) << 4);
            *(_Float16*)(tile + addr) = (_Float16)v[j];
        }
    }
    __syncthreads();
    char* dst = (char*)Bp + (size_t)t * TILE_BYTES;
#pragma unroll
    for (int v = 0; v < 8; ++v) {
        int off = (v * 256 + tid) * 16;           // coalesced 16B copy out
        *(f32x4*)(dst + off) = *(const f32x4*)(tile + off);
    }
}

// ---------------- main GEMM: BM=128, BN=128, 8 waves (2x4), 3x16KB ring --------------
// grid 512 = 8 K-slabs (==XCD) x 32 mt x 2 nt; 64KB LDS/block -> 2 blocks/CU.
__global__ __launch_bounds__(512, 4) void k_gemm(
        const _Float16* __restrict__ hb, const float* __restrict__ hypT,
        const _Float16* __restrict__ Bp, float* __restrict__ out) {
    __shared__ char smem[65536];   // slots 0/1/2 at s*16384; shyp f16 at 49152

    const int tid  = threadIdx.x;
    const int lane = tid & 63;
    const int wid  = tid >> 6;                 // 8 waves
    const int wm   = wid >> 2, wn = wid & 3;   // 2 x 4 wave grid, 64x32 out each
    const int l15  = lane & 15, lg = lane >> 4;

    const int bid  = blockIdx.x;               // 512
    const int s    = bid & 7;                  // K-slab == XCD (round-robin dispatch)
    const int rest = bid >> 3;                 // 0..63
    const int nt   = rest & 1;
    const int mt   = rest >> 1;                // 0..31
    const int k0   = s * 64;
    const int row_base = mt * 128;
    const int NT   = (s == 7) ? 260 : 256;     // slab 7 owns the 4 b2 tiles

    _Float16* shyp = (_Float16*)(smem + 49152);   // [64 kk][128 r] f16

    // ---- prologue: hyp slab -> LDS as f16 (one-time) ----
#pragma unroll
    for (int u = 0; u < 4; ++u) {
        int f  = (u * 512 + tid) * 4;          // 8192 floats
        int kk = f >> 7;
        int r  = f & 127;
        f32x4 v = *(const f32x4*)(hypT + (size_t)(k0 + kk) * 4096 + row_base + r);
        f16x4 o;
        o[0] = (_Float16)v[0]; o[1] = (_Float16)v[1];
        o[2] = (_Float16)v[2]; o[3] = (_Float16)v[3];
        *(f16x4*)(shyp + kk * 128 + r) = o;
    }

    auto tile_of = [&](int idx) {
        return (idx < 256) ? ((k0 + (idx & 63)) * 4 + (idx >> 6)) : (2048 + idx - 256);
    };
    // stage this block's 16KB half-tile (cols nt*128..+128) into ring slot
    auto stage = [&](int slot, int t) {
        const char* gsrc = (const char*)Bp + (size_t)t * TILE_BYTES + (nt << 14)
                         + wid * 2048 + lane * 16;
        char* ldst = smem + slot * 16384 + wid * 2048;   // wave-uniform base, lane*16 implicit
#pragma unroll
        for (int q = 0; q < 2; ++q)
            __builtin_amdgcn_global_load_lds(
                (const __attribute__((address_space(1))) void*)(gsrc + q * 1024),
                (__attribute__((address_space(3))) void*)(ldst + q * 1024), 16, 0, 0);
    };

    stage(0, tile_of(0));
    stage(1, tile_of(1));
    asm volatile("s_waitcnt vmcnt(0) lgkmcnt(0)" ::: "memory");  // tiles 0,1 + shyp ready
    __builtin_amdgcn_s_barrier();

    f32x4 acc[4][2];
#pragma unroll
    for (int i = 0; i < 4; ++i)
#pragma unroll
        for (int j = 0; j < 2; ++j)
#pragma unroll
            for (int q = 0; q < 4; ++q) acc[i][j][q] = 0.0f;

    int slot = 0;   // ring: read slot = idx%3

    for (int G = 0; G < 8; ++G) {              // 0..3 main (64 iters), 4..7 b2 tail (s==7)
        if (G >= 4 && s != 7) break;
        const int niter = (G < 4) ? 64 : 1;

        // A-frags for this i0-group: 8 direct f16 16B loads (wave's 64 rows)
        f16x8 af[4][2];
#pragma unroll
        for (int mf = 0; mf < 4; ++mf)
#pragma unroll
            for (int ks = 0; ks < 2; ++ks)
                af[mf][ks] = *(const f16x8*)(hb + (size_t)(row_base + wm * 64 + mf * 16 + l15) * 256
                                             + (G & 3) * 64 + ks * 32 + lg * 8);

        for (int jj = 0; jj < niter; ++jj) {
            const int idx = (G < 4) ? G * 64 + jj : 256 + (G - 4);
            const bool do_stage = (idx + 2 < NT);
            if (do_stage) {
                int st = (slot + 2 >= 3) ? slot - 1 : slot + 2;   // (idx+2)%3
                stage(st, tile_of(idx + 2));
            }

            // B-frags from current ring slot (swizzled ds_read_b128); cols rel. to block
            const char* sB = smem + slot * 16384;
            f16x8 b0[2], b1[2];
#pragma unroll
            for (int nf = 0; nf < 2; ++nf) {
                int col = wn * 32 + nf * 16 + l15;
                int swz = (col & 7) << 4;
                b0[nf] = *(const f16x8*)(sB + ((col * 128 + lg * 16) ^ swz));
                b1[nf] = *(const f16x8*)(sB + ((col * 128 + 64 + lg * 16) ^ swz));
            }
            // per-lane A-row scale (broadcast ds_read_u16, conflict-free)
            _Float16 sch[4];
            if (idx < 256) {
#pragma unroll
                for (int mf = 0; mf < 4; ++mf)
                    sch[mf] = shyp[jj * 128 + wm * 64 + mf * 16 + l15];
            } else {
#pragma unroll
                for (int mf = 0; mf < 4; ++mf) sch[mf] = (_Float16)1.0f;
            }

            __builtin_amdgcn_s_setprio(1);
#pragma unroll
            for (int mf = 0; mf < 4; ++mf) {
                f16x8 as0 = af[mf][0] * sch[mf];   // v_pk_mul_f16 x4
                f16x8 as1 = af[mf][1] * sch[mf];
#pragma unroll
                for (int nf = 0; nf < 2; ++nf)
                    acc[mf][nf] = __builtin_amdgcn_mfma_f32_16x16x32_f16(as0, b0[nf], acc[mf][nf], 0, 0, 0);
#pragma unroll
                for (int nf = 0; nf < 2; ++nf)
                    acc[mf][nf] = __builtin_amdgcn_mfma_f32_16x16x32_f16(as1, b1[nf], acc[mf][nf], 0, 0, 0);
            }
            __builtin_amdgcn_s_setprio(0);

            // counted wait: idx+1's 2 loads landed, idx+2's 2 stay in flight
            if (do_stage) asm volatile("s_waitcnt vmcnt(2)" ::: "memory");
            else          asm volatile("s_waitcnt vmcnt(0)" ::: "memory");
            __builtin_amdgcn_s_barrier();

            slot = (slot + 1 >= 3) ? 0 : slot + 1;
        }
    }

    // ---- epilogue: atomic split-K accumulate (out pre-initialized with bias) ----
    int crow0 = row_base + wm * 64;
    int ccol0 = nt * 128 + wn * 32;
#pragma unroll
    for (int mf = 0; mf < 4; ++mf)
#pragma unroll
        for (int nf = 0; nf < 2; ++nf) {
            int col = ccol0 + nf * 16 + l15;
#pragma unroll
            for (int q = 0; q < 4; ++q) {
                int row = crow0 + mf * 16 + lg * 4 + q;   // C/D: col=lane&15, row=(lane>>4)*4+q
                atomicAdd(&out[row * 256 + col], acc[mf][nf][q]);
            }
        }
}

extern "C" void kernel_launch(void* const* d_in, const int* in_sizes, int n_in,
                              void* d_out, int out_size, void* d_ws, size_t ws_size,
                              hipStream_t stream) {
    const float* h    = (const float*)d_in[0];  // [4096,256]
    const float* z    = (const float*)d_in[1];  // [4096,128]
    const float* W1   = (const float*)d_in[2];  // [128,512]
    const float* b1   = (const float*)d_in[3];  // [512]
    const float* W2   = (const float*)d_in[4];  // [512,65536]
    const float* b2   = (const float*)d_in[5];  // [65536]
    const float* bias = (const float*)d_in[6];  // [1,256]
    float* out = (float*)d_out;                 // [4096,256] fp32

    float*     hypT = (float*)d_ws;                          // 513*4096*4 = 8.4 MB
    _Float16*  hb   = (_Float16*)((char*)d_ws + HB_OFF);     // 2 MB f16 h
    _Float16*  Bp   = (_Float16*)((char*)d_ws + BP_OFF);     // 67.2 MB

    k_pack    <<<KTILES, 256, 0, stream>>>(W2, b2, Bp);
    k_hypT    <<<129,    512, 0, stream>>>(z, W1, b1, hypT);
    k_hcast   <<<512,    256, 0, stream>>>(h, hb);
    k_init_out<<<4096,   256, 0, stream>>>(bias, out);
    k_gemm    <<<512,    512, 0, stream>>>(hb, hypT, Bp, out);
}

// Round 9
// 316.174 us; speedup vs baseline: 1.1138x; 1.1138x over previous
//
#include <hip/hip_runtime.h>
#include <hip/hip_bf16.h>
#include <stdint.h>

// out[b,o] = sum_{k,i} hyp[b,k]*h[b,i]*W2[k,i*256+o] + sum_i h[b,i]*b2[i*256+o] + bias[o]
// GEMM A[4096 x 131328] * B[131328 x 256], A = diag(hyp_k)*H per k-group — all FP16.
// A-frag scaled in regs (v_pk_mul_f16, row is lane-local), MFMA accumulates via C operand.
// BARRIER-FREE K-loop: 1x8 wave grid — each wave stages exactly the 4KB tile-slice it
// reads (cols [wid*32,+32) == bytes [wid*4096,+4096)), so the 3-slot LDS ring is a
// per-wave private pipeline ordered by per-wave vmcnt alone. One barrier total (shyp).
// ws: [0,8.4M) hypT fp32 [513][4096] (row 512 = ones, folds b2); [9M,+2M) h f16; [12M,+67.2M) packed B.

typedef _Float16 f16x8 __attribute__((ext_vector_type(8)));
typedef _Float16 f16x4 __attribute__((ext_vector_type(4)));
typedef float    f32x4 __attribute__((ext_vector_type(4)));

#define KTILES     2052
#define TILE_BYTES 32768          // 256 cols * 64 k * 2B
#define HB_OFF     (9u*1024u*1024u)
#define BP_OFF     (12u*1024u*1024u)

// ---------------- out = bias ----------------
__global__ void k_init_out(const float* __restrict__ bias, float* __restrict__ out) {
    int idx = blockIdx.x * 256 + threadIdx.x;
    out[idx] = bias[idx & 255];
}

// ---------------- h fp32 -> f16 ----------------
__global__ void k_hcast(const float* __restrict__ h, _Float16* __restrict__ hb) {
    int i = (blockIdx.x * 256 + threadIdx.x) * 8;    // grid 512 x 256
    f32x4 a = *(const f32x4*)(h + i);
    f32x4 b = *(const f32x4*)(h + i + 4);
    f16x8 v;
    v[0] = (_Float16)a[0]; v[1] = (_Float16)a[1]; v[2] = (_Float16)a[2]; v[3] = (_Float16)a[3];
    v[4] = (_Float16)b[0]; v[5] = (_Float16)b[1]; v[6] = (_Float16)b[2]; v[7] = (_Float16)b[3];
    *(f16x8*)(hb + i) = v;
}

// ---------------- hypT[k][b] = relu(z@W1+b1)^T; row 512 = 1.0 ----------------
__global__ void k_hypT(const float* __restrict__ z, const float* __restrict__ W1,
                       const float* __restrict__ b1, float* __restrict__ hypT) {
    int blk = blockIdx.x;
    int t   = threadIdx.x;                       // 512 threads; t == k
    if (blk == 128) {                            // ones row (b2 scale)
#pragma unroll
        for (int r = 0; r < 8; ++r) hypT[(size_t)512*4096 + r*512 + t] = 1.0f;
        return;
    }
    __shared__ float zs[32][128];
    int b0 = blk * 32;
#pragma unroll
    for (int u = 0; u < 8; ++u) {
        int idx = u * 512 + t;
        zs[idx >> 7][idx & 127] = z[b0 * 128 + idx];
    }
    __syncthreads();
    float acc[32];
    float bk = b1[t];
#pragma unroll
    for (int b = 0; b < 32; ++b) acc[b] = bk;
    for (int c = 0; c < 128; ++c) {
        float w = W1[c * 512 + t];
#pragma unroll
        for (int b = 0; b < 32; ++b) acc[b] = fmaf(zs[b][c], w, acc[b]);
    }
    float* dst = hypT + (size_t)t * 4096 + b0;
#pragma unroll
    for (int v = 0; v < 8; ++v) {
        f32x4 o;
#pragma unroll
        for (int q = 0; q < 4; ++q) {
            float a = acc[v * 4 + q];
            o[q] = a > 0.f ? a : 0.f;
        }
        *(f32x4*)(dst + v * 4) = o;
    }
}

// ---------------- pack W2 (+b2) -> f16 transposed+swizzled tiles ----------------
// dst element (kk,o) at byte (o*128 + kk*2) ^ ((o&7)<<4); build in LDS, stream out 16B.
__global__ void k_pack(const float* __restrict__ W2, const float* __restrict__ b2,
                       _Float16* __restrict__ Bp) {
    __shared__ char tile[TILE_BYTES];
    int t   = blockIdx.x;
    int tid = threadIdx.x;        // 256
    long row0 = (long)t * 64;
    const float* src = (t < 2048) ? (W2 + row0 * 256) : (b2 + (row0 - 131072) * 256);
#pragma unroll
    for (int u = 0; u < 16; ++u) {
        int f = (u * 256 + tid) * 4;              // flat fp32 idx, coalesced
        f32x4 v = *(const f32x4*)(src + f);
        int kk = f >> 8;
        int o0 = f & 255;
#pragma unroll
        for (int j = 0; j < 4; ++j) {
            int o = o0 + j;
            int addr = (o * 128 + kk * 2) ^ ((o & 7) << 4);
            *(_Float16*)(tile + addr) = (_Float16)v[j];
        }
    }
    __syncthreads();
    char* dst = (char*)Bp + (size_t)t * TILE_BYTES;
#pragma unroll
    for (int v = 0; v < 8; ++v) {
        int off = (v * 256 + tid) * 16;           // coalesced 16B copy out
        *(f32x4*)(dst + off) = *(const f32x4*)(tile + off);
    }
}

// ---------------- main GEMM: BM=128, BN=256, 8 waves (1x8), barrier-free ring --------
// grid 256 = 8 K-slabs (==XCD) x 32 mt; LDS = 3x32KB ring + 16KB shyp(f16) = 112KB.
__global__ __launch_bounds__(512, 1) void k_gemm(
        const _Float16* __restrict__ hb, const float* __restrict__ hypT,
        const _Float16* __restrict__ Bp, float* __restrict__ out) {
    __shared__ char smem[114688];   // slots 0/1/2 at s*32768; shyp f16 at 98304

    const int tid  = threadIdx.x;
    const int lane = tid & 63;
    const int wid  = tid >> 6;                 // 8 waves; wave owns cols [wid*32,+32)
    const int l15  = lane & 15, lg = lane >> 4;

    const int bid = blockIdx.x;                // 256
    const int s   = bid & 7;                   // K-slab == XCD (round-robin dispatch)
    const int mt  = bid >> 3;                  // 0..31
    const int k0  = s * 64;
    const int row_base = mt * 128;
    const int NT  = (s == 7) ? 260 : 256;      // slab 7 owns the 4 b2 tiles

    _Float16* shyp = (_Float16*)(smem + 98304);   // [64 kk][128 r] f16

    // ---- prologue: hyp slab -> LDS as f16 (one-time) ----
#pragma unroll
    for (int u = 0; u < 4; ++u) {
        int f  = (u * 512 + tid) * 4;          // 8192 floats
        int kk = f >> 7;
        int r  = f & 127;
        f32x4 v = *(const f32x4*)(hypT + (size_t)(k0 + kk) * 4096 + row_base + r);
        f16x4 o;
        o[0] = (_Float16)v[0]; o[1] = (_Float16)v[1];
        o[2] = (_Float16)v[2]; o[3] = (_Float16)v[3];
        *(f16x4*)(shyp + kk * 128 + r) = o;
    }

    auto tile_of = [&](int idx) {
        return (idx < 256) ? ((k0 + (idx & 63)) * 4 + (idx >> 6)) : (2048 + idx - 256);
    };
    // wave stages ITS OWN 4KB slice (cols [wid*32,+32)) of the 32KB tile
    auto stage = [&](int slot, int t) {
        const char* gsrc = (const char*)Bp + (size_t)t * TILE_BYTES + wid * 4096 + lane * 16;
        char* ldst = smem + slot * 32768 + wid * 4096;   // wave-uniform base, lane*16 implicit
#pragma unroll
        for (int q = 0; q < 4; ++q)
            __builtin_amdgcn_global_load_lds(
                (const __attribute__((address_space(1))) void*)(gsrc + q * 1024),
                (__attribute__((address_space(3))) void*)(ldst + q * 1024), 16, 0, 0);
    };

    stage(0, tile_of(0));
    stage(1, tile_of(1));
    __syncthreads();               // shyp visibility (the ONLY block-wide barrier)

    f32x4 acc[8][2];
#pragma unroll
    for (int i = 0; i < 8; ++i)
#pragma unroll
        for (int j = 0; j < 2; ++j)
#pragma unroll
            for (int q = 0; q < 4; ++q) acc[i][j][q] = 0.0f;

    int slot = 0;   // read slot = idx%3

    for (int G = 0; G < 8; ++G) {              // 0..3 main (64 iters), 4..7 b2 tail (s==7)
        if (G >= 4 && s != 7) break;
        const int niter = (G < 4) ? 64 : 1;

        // A-frags for this i0-group: 16 direct f16 16B loads (all 128 rows)
        f16x8 af[8][2];
#pragma unroll
        for (int mf = 0; mf < 8; ++mf)
#pragma unroll
            for (int ks = 0; ks < 2; ++ks)
                af[mf][ks] = *(const f16x8*)(hb + (size_t)(row_base + mf * 16 + l15) * 256
                                             + (G & 3) * 64 + ks * 32 + lg * 8);

        for (int jj = 0; jj < niter; ++jj) {
            const int idx = (G < 4) ? G * 64 + jj : 256 + (G - 4);

            // prefetch idx+2 into slot freed by this wave's own idx-1 reads
            if (idx + 2 < NT) {
                int st = (slot + 2 >= 3) ? slot - 1 : slot + 2;   // (idx+2)%3
                stage(st, tile_of(idx + 2));
            }
            // per-wave counted wait: tile idx's 4 loads retired; newer stay in flight
            if (idx + 2 < NT)      asm volatile("s_waitcnt vmcnt(8)" ::: "memory");
            else if (idx + 1 < NT) asm volatile("s_waitcnt vmcnt(4)" ::: "memory");
            else                   asm volatile("s_waitcnt vmcnt(0)" ::: "memory");

            // B-frags from own slice of current slot (swizzled ds_read_b128)
            const char* sB = smem + slot * 32768;
            f16x8 b0[2], b1[2];
#pragma unroll
            for (int nf = 0; nf < 2; ++nf) {
                int col = wid * 32 + nf * 16 + l15;
                int swz = (col & 7) << 4;
                b0[nf] = *(const f16x8*)(sB + ((col * 128 + lg * 16) ^ swz));
                b1[nf] = *(const f16x8*)(sB + ((col * 128 + 64 + lg * 16) ^ swz));
            }
            // per-lane A-row scales (broadcast ds_read_u16, 2-way max -> free)
            _Float16 sch[8];
            if (idx < 256) {
#pragma unroll
                for (int mf = 0; mf < 8; ++mf)
                    sch[mf] = shyp[jj * 128 + mf * 16 + l15];
            } else {
#pragma unroll
                for (int mf = 0; mf < 8; ++mf) sch[mf] = (_Float16)1.0f;
            }

            __builtin_amdgcn_s_setprio(1);
#pragma unroll
            for (int mf = 0; mf < 8; ++mf) {
                f16x8 as0 = af[mf][0] * sch[mf];   // v_pk_mul_f16 x4
                f16x8 as1 = af[mf][1] * sch[mf];
                acc[mf][0] = __builtin_amdgcn_mfma_f32_16x16x32_f16(as0, b0[0], acc[mf][0], 0, 0, 0);
                acc[mf][1] = __builtin_amdgcn_mfma_f32_16x16x32_f16(as0, b0[1], acc[mf][1], 0, 0, 0);
                acc[mf][0] = __builtin_amdgcn_mfma_f32_16x16x32_f16(as1, b1[0], acc[mf][0], 0, 0, 0);
                acc[mf][1] = __builtin_amdgcn_mfma_f32_16x16x32_f16(as1, b1[1], acc[mf][1], 0, 0, 0);
            }
            __builtin_amdgcn_s_setprio(0);

            slot = (slot + 1 >= 3) ? 0 : slot + 1;
        }
    }

    // ---- epilogue: atomic split-K accumulate (out pre-initialized with bias) ----
#pragma unroll
    for (int mf = 0; mf < 8; ++mf)
#pragma unroll
        for (int nf = 0; nf < 2; ++nf) {
            int col = wid * 32 + nf * 16 + l15;
#pragma unroll
            for (int q = 0; q < 4; ++q) {
                int row = row_base + mf * 16 + lg * 4 + q;  // C/D: col=lane&15, row=(lane>>4)*4+q
                atomicAdd(&out[row * 256 + col], acc[mf][nf][q]);
            }
        }
}

extern "C" void kernel_launch(void* const* d_in, const int* in_sizes, int n_in,
                              void* d_out, int out_size, void* d_ws, size_t ws_size,
                              hipStream_t stream) {
    const float* h    = (const float*)d_in[0];  // [4096,256]
    const float* z    = (const float*)d_in[1];  // [4096,128]
    const float* W1   = (const float*)d_in[2];  // [128,512]
    const float* b1   = (const float*)d_in[3];  // [512]
    const float* W2   = (const float*)d_in[4];  // [512,65536]
    const float* b2   = (const float*)d_in[5];  // [65536]
    const float* bias = (const float*)d_in[6];  // [1,256]
    float* out = (float*)d_out;                 // [4096,256] fp32

    float*     hypT = (float*)d_ws;                          // 513*4096*4 = 8.4 MB
    _Float16*  hb   = (_Float16*)((char*)d_ws + HB_OFF);     // 2 MB f16 h
    _Float16*  Bp   = (_Float16*)((char*)d_ws + BP_OFF);     // 67.2 MB

    k_pack    <<<KTILES, 256, 0, stream>>>(W2, b2, Bp);
    k_hypT    <<<129,    512, 0, stream>>>(z, W1, b1, hypT);
    k_hcast   <<<512,    256, 0, stream>>>(h, hb);
    k_init_out<<<4096,   256, 0, stream>>>(bias, out);
    k_gemm    <<<256,    512, 0, stream>>>(hb, hypT, Bp, out);
}

// Round 10
// 306.582 us; speedup vs baseline: 1.1487x; 1.0313x over previous
//
#include <hip/hip_runtime.h>
#include <hip/hip_bf16.h>
#include <stdint.h>

// out[b,o] = sum_{k,i} hyp[b,k]*h[b,i]*W2[k,i*256+o] + sum_i h[b,i]*b2[i*256+o] + bias[o]
// GEMM A[4096 x 131328] * B[131328 x 256], A = diag(hyp_k)*H per k-group — all FP16.
// A-frag scaled in regs (v_pk_mul_f16), MFMA accumulates via C operand.
// BARRIER-FREE K-loop (1x8 wave grid: each wave stages exactly the 4KB slice it reads)
// + REGISTER DOUBLE-BUFFER: iteration idx's MFMA overlaps the ds_reads for idx+1
// (named A/B register sets, 2-step unrolled body). 4-slot LDS ring, stage depth 3,
// counted per-wave vmcnt(8). One block-wide barrier total (shyp visibility).
// ws: [0,8.4M) hypT fp32 [513][4096] (row 512 = ones, folds b2); [9M,+2M) h f16; [12M,+67.2M) packed B.

typedef _Float16 f16x8 __attribute__((ext_vector_type(8)));
typedef _Float16 f16x4 __attribute__((ext_vector_type(4)));
typedef float    f32x4 __attribute__((ext_vector_type(4)));

#define KTILES     2052
#define TILE_BYTES 32768          // 256 cols * 64 k * 2B
#define HB_OFF     (9u*1024u*1024u)
#define BP_OFF     (12u*1024u*1024u)

// ---------------- out = bias ----------------
__global__ void k_init_out(const float* __restrict__ bias, float* __restrict__ out) {
    int idx = blockIdx.x * 256 + threadIdx.x;
    out[idx] = bias[idx & 255];
}

// ---------------- h fp32 -> f16 ----------------
__global__ void k_hcast(const float* __restrict__ h, _Float16* __restrict__ hb) {
    int i = (blockIdx.x * 256 + threadIdx.x) * 8;    // grid 512 x 256
    f32x4 a = *(const f32x4*)(h + i);
    f32x4 b = *(const f32x4*)(h + i + 4);
    f16x8 v;
    v[0] = (_Float16)a[0]; v[1] = (_Float16)a[1]; v[2] = (_Float16)a[2]; v[3] = (_Float16)a[3];
    v[4] = (_Float16)b[0]; v[5] = (_Float16)b[1]; v[6] = (_Float16)b[2]; v[7] = (_Float16)b[3];
    *(f16x8*)(hb + i) = v;
}

// ---------------- hypT[k][b] = relu(z@W1+b1)^T; row 512 = 1.0 ----------------
__global__ void k_hypT(const float* __restrict__ z, const float* __restrict__ W1,
                       const float* __restrict__ b1, float* __restrict__ hypT) {
    int blk = blockIdx.x;
    int t   = threadIdx.x;                       // 512 threads; t == k
    if (blk == 128) {                            // ones row (b2 scale)
#pragma unroll
        for (int r = 0; r < 8; ++r) hypT[(size_t)512*4096 + r*512 + t] = 1.0f;
        return;
    }
    __shared__ float zs[32][128];
    int b0 = blk * 32;
#pragma unroll
    for (int u = 0; u < 8; ++u) {
        int idx = u * 512 + t;
        zs[idx >> 7][idx & 127] = z[b0 * 128 + idx];
    }
    __syncthreads();
    float acc[32];
    float bk = b1[t];
#pragma unroll
    for (int b = 0; b < 32; ++b) acc[b] = bk;
    for (int c = 0; c < 128; ++c) {
        float w = W1[c * 512 + t];
#pragma unroll
        for (int b = 0; b < 32; ++b) acc[b] = fmaf(zs[b][c], w, acc[b]);
    }
    float* dst = hypT + (size_t)t * 4096 + b0;
#pragma unroll
    for (int v = 0; v < 8; ++v) {
        f32x4 o;
#pragma unroll
        for (int q = 0; q < 4; ++q) {
            float a = acc[v * 4 + q];
            o[q] = a > 0.f ? a : 0.f;
        }
        *(f32x4*)(dst + v * 4) = o;
    }
}

// ---------------- pack W2 (+b2) -> f16 transposed+swizzled tiles ----------------
// dst element (kk,o) at byte (o*128 + kk*2) ^ ((o&7)<<4); build in LDS, stream out 16B.
__global__ void k_pack(const float* __restrict__ W2, const float* __restrict__ b2,
                       _Float16* __restrict__ Bp) {
    __shared__ char tile[TILE_BYTES];
    int t   = blockIdx.x;
    int tid = threadIdx.x;        // 256
    long row0 = (long)t * 64;
    const float* src = (t < 2048) ? (W2 + row0 * 256) : (b2 + (row0 - 131072) * 256);
#pragma unroll
    for (int u = 0; u < 16; ++u) {
        int f = (u * 256 + tid) * 4;              // flat fp32 idx, coalesced
        f32x4 v = *(const f32x4*)(src + f);
        int kk = f >> 8;
        int o0 = f & 255;
#pragma unroll
        for (int j = 0; j < 4; ++j) {
            int o = o0 + j;
            int addr = (o * 128 + kk * 2) ^ ((o & 7) << 4);
            *(_Float16*)(tile + addr) = (_Float16)v[j];
        }
    }
    __syncthreads();
    char* dst = (char*)Bp + (size_t)t * TILE_BYTES;
#pragma unroll
    for (int v = 0; v < 8; ++v) {
        int off = (v * 256 + tid) * 16;           // coalesced 16B copy out
        *(f32x4*)(dst + off) = *(const f32x4*)(tile + off);
    }
}

// ---------------- main GEMM: BM=128, BN=256, 8 waves (1x8), reg-dbuf pipeline --------
// grid 256 = 8 K-slabs (==XCD) x 32 mt; LDS = 4x32KB ring + 16KB shyp = 144KB.
__global__ __launch_bounds__(512, 2) void k_gemm(
        const _Float16* __restrict__ hb, const float* __restrict__ hypT,
        const _Float16* __restrict__ Bp, float* __restrict__ out) {
    __shared__ char smem[147456];   // slots 0..3 at s*32768; shyp f16 at 131072

    const int tid  = threadIdx.x;
    const int lane = tid & 63;
    const int wid  = tid >> 6;                 // 8 waves; wave owns cols [wid*32,+32)
    const int l15  = lane & 15, lg = lane >> 4;

    const int bid = blockIdx.x;                // 256
    const int s   = bid & 7;                   // K-slab == XCD (round-robin dispatch)
    const int mt  = bid >> 3;                  // 0..31
    const int k0  = s * 64;
    const int row_base = mt * 128;
    const int NT  = (s == 7) ? 260 : 256;      // slab 7 owns the 4 b2 tiles

    _Float16* shyp = (_Float16*)(smem + 131072);   // [64 kk][16 l15][8 mf] f16

    // ---- prologue: hyp slab -> LDS, transposed so a lane's 8 scales are one b128 ----
#pragma unroll
    for (int u = 0; u < 4; ++u) {
        int f  = (u * 512 + tid) * 4;          // 8192 floats
        int kk = f >> 7;
        int r  = f & 127;
        f32x4 v = *(const f32x4*)(hypT + (size_t)(k0 + kk) * 4096 + row_base + r);
#pragma unroll
        for (int q = 0; q < 4; ++q) {
            int rr = r + q;                    // rr = mf*16 + l15
            shyp[kk * 128 + (rr & 15) * 8 + (rr >> 4)] = (_Float16)v[q];
        }
    }

    auto tile_of = [&](int idx) {
        return (idx < 256) ? ((k0 + (idx & 63)) * 4 + (idx >> 6)) : (2048 + idx - 256);
    };
    // wave stages ITS OWN 4KB slice (cols [wid*32,+32)) of the 32KB tile
    auto stage = [&](int slot, int t) {
        const char* gsrc = (const char*)Bp + (size_t)t * TILE_BYTES + wid * 4096 + lane * 16;
        char* ldst = smem + slot * 32768 + wid * 4096;   // wave-uniform base, lane*16 implicit
#pragma unroll
        for (int q = 0; q < 4; ++q)
            __builtin_amdgcn_global_load_lds(
                (const __attribute__((address_space(1))) void*)(gsrc + q * 1024),
                (__attribute__((address_space(3))) void*)(ldst + q * 1024), 16, 0, 0);
    };

    stage(0, tile_of(0));
    stage(1, tile_of(1));
    stage(2, tile_of(2));
    __syncthreads();               // shyp visibility (drains vmcnt too; one-time)

    f32x4 acc[8][2];
#pragma unroll
    for (int i = 0; i < 8; ++i)
#pragma unroll
        for (int j = 0; j < 2; ++j)
#pragma unroll
            for (int q = 0; q < 4; ++q) acc[i][j][q] = 0.0f;

    f16x8 one8;
#pragma unroll
    for (int q = 0; q < 8; ++q) one8[q] = (_Float16)1.0f;

    // register double-buffer sets
    f16x8 cA0[2], cA1[2], cB0[2], cB1[2];
    f16x8 scA, scB;
    f16x8 af[8][2];

    // ---- read tile 0's fragments + scales into set A ----
    {
        const char* sB = smem;     // slot 0
#pragma unroll
        for (int nf = 0; nf < 2; ++nf) {
            int col = wid * 32 + nf * 16 + l15;
            int swz = (col & 7) << 4;
            cA0[nf] = *(const f16x8*)(sB + ((col * 128 + lg * 16) ^ swz));
            cA1[nf] = *(const f16x8*)(sB + ((col * 128 + 64 + lg * 16) ^ swz));
        }
        scA = *(const f16x8*)(shyp + l15 * 8);
    }

// one pipeline step: MFMA on CUR set while staging idx+3 and reading idx+1 into NXT set
#define PIPE(C0, C1, SC, N0, N1, SN, IDX)                                                     \
  {                                                                                           \
    const int _i = (IDX);                                                                     \
    if (_i + 3 < NT) stage((_i + 3) & 3, tile_of(_i + 3));                                    \
    if (_i + 1 < NT) {                                                                        \
      int _stg  = (_i + 3 < NT) ? _i + 3 : NT - 1;                                            \
      int _pend = _stg - (_i + 1);                                                            \
      if (_pend >= 2)      asm volatile("s_waitcnt vmcnt(8)" ::: "memory");                   \
      else if (_pend == 1) asm volatile("s_waitcnt vmcnt(4)" ::: "memory");                   \
      else                 asm volatile("s_waitcnt vmcnt(0)" ::: "memory");                   \
      const char* _sB = smem + ((_i + 1) & 3) * 32768;                                        \
      _Pragma("unroll")                                                                       \
      for (int nf = 0; nf < 2; ++nf) {                                                        \
        int col = wid * 32 + nf * 16 + l15;                                                   \
        int swz = (col & 7) << 4;                                                             \
        N0[nf] = *(const f16x8*)(_sB + ((col * 128 + lg * 16) ^ swz));                        \
        N1[nf] = *(const f16x8*)(_sB + ((col * 128 + 64 + lg * 16) ^ swz));                   \
      }                                                                                       \
      if (_i + 1 < 256) SN = *(const f16x8*)(shyp + ((_i + 1) & 63) * 128 + l15 * 8);         \
      else              SN = one8;                                                           \
    }                                                                                         \
    __builtin_amdgcn_s_setprio(1);                                                            \
    _Pragma("unroll")                                                                         \
    for (int mf = 0; mf < 8; ++mf) {                                                          \
      f16x8 _a0 = C0##f(mf);                                                                  \
      f16x8 _a1 = C1##f(mf);                                                                  \
      acc[mf][0] = __builtin_amdgcn_mfma_f32_16x16x32_f16(_a0, C0[0], acc[mf][0], 0, 0, 0);   \
      acc[mf][1] = __builtin_amdgcn_mfma_f32_16x16x32_f16(_a0, C0[1], acc[mf][1], 0, 0, 0);   \
      acc[mf][0] = __builtin_amdgcn_mfma_f32_16x16x32_f16(_a1, C1[0], acc[mf][0], 0, 0, 0);   \
      acc[mf][1] = __builtin_amdgcn_mfma_f32_16x16x32_f16(_a1, C1[1], acc[mf][1], 0, 0, 0);   \
    }                                                                                         \
    __builtin_amdgcn_s_setprio(0);                                                            \
  }
// helpers: scaled A fragments for the two k-halves
#define cA0f(mf) (af[mf][0] * scA[mf])
#define cA1f(mf) (af[mf][1] * scA[mf])
#define cB0f(mf) (af[mf][0] * scB[mf])
#define cB1f(mf) (af[mf][1] * scB[mf])

    for (int G = 0; G < 4; ++G) {
        // A-frags for this i0-group: 16 direct f16 16B loads (all 128 rows)
#pragma unroll
        for (int mf = 0; mf < 8; ++mf)
#pragma unroll
            for (int ks = 0; ks < 2; ++ks)
                af[mf][ks] = *(const f16x8*)(hb + (size_t)(row_base + mf * 16 + l15) * 256
                                             + G * 64 + ks * 32 + lg * 8);

        for (int jj = 0; jj < 64; jj += 2) {
            const int idx = G * 64 + jj;
            PIPE(cA0, cA1, scA, cB0, cB1, scB, idx);
            PIPE(cB0, cB1, scB, cA0, cA1, scA, idx + 1);
        }
    }

    // ---- b2 tail (slab 7 only): tiles 256..259, scale 1 ----
    if (s == 7) {
        for (int g = 0; g < 4; ++g) {
            int idx = 256 + g;
            if (idx + 3 < 260) stage((idx + 3) & 3, tile_of(idx + 3));
            asm volatile("s_waitcnt vmcnt(0)" ::: "memory");
            f16x8 tf[8][2];
#pragma unroll
            for (int mf = 0; mf < 8; ++mf)
#pragma unroll
                for (int ks = 0; ks < 2; ++ks)
                    tf[mf][ks] = *(const f16x8*)(hb + (size_t)(row_base + mf * 16 + l15) * 256
                                                 + g * 64 + ks * 32 + lg * 8);
            const char* sB = smem + (idx & 3) * 32768;
            f16x8 t0[2], t1[2];
#pragma unroll
            for (int nf = 0; nf < 2; ++nf) {
                int col = wid * 32 + nf * 16 + l15;
                int swz = (col & 7) << 4;
                t0[nf] = *(const f16x8*)(sB + ((col * 128 + lg * 16) ^ swz));
                t1[nf] = *(const f16x8*)(sB + ((col * 128 + 64 + lg * 16) ^ swz));
            }
#pragma unroll
            for (int mf = 0; mf < 8; ++mf) {
                acc[mf][0] = __builtin_amdgcn_mfma_f32_16x16x32_f16(tf[mf][0], t0[0], acc[mf][0], 0, 0, 0);
                acc[mf][1] = __builtin_amdgcn_mfma_f32_16x16x32_f16(tf[mf][0], t0[1], acc[mf][1], 0, 0, 0);
                acc[mf][0] = __builtin_amdgcn_mfma_f32_16x16x32_f16(tf[mf][1], t1[0], acc[mf][0], 0, 0, 0);
                acc[mf][1] = __builtin_amdgcn_mfma_f32_16x16x32_f16(tf[mf][1], t1[1], acc[mf][1], 0, 0, 0);
            }
        }
    }

    // ---- epilogue: atomic split-K accumulate (out pre-initialized with bias) ----
#pragma unroll
    for (int mf = 0; mf < 8; ++mf)
#pragma unroll
        for (int nf = 0; nf < 2; ++nf) {
            int col = wid * 32 + nf * 16 + l15;
#pragma unroll
            for (int q = 0; q < 4; ++q) {
                int row = row_base + mf * 16 + lg * 4 + q;  // C/D: col=lane&15, row=(lane>>4)*4+q
                atomicAdd(&out[row * 256 + col], acc[mf][nf][q]);
            }
        }
}

extern "C" void kernel_launch(void* const* d_in, const int* in_sizes, int n_in,
                              void* d_out, int out_size, void* d_ws, size_t ws_size,
                              hipStream_t stream) {
    const float* h    = (const float*)d_in[0];  // [4096,256]
    const float* z    = (const float*)d_in[1];  // [4096,128]
    const float* W1   = (const float*)d_in[2];  // [128,512]
    const float* b1   = (const float*)d_in[3];  // [512]
    const float* W2   = (const float*)d_in[4];  // [512,65536]
    const float* b2   = (const float*)d_in[5];  // [65536]
    const float* bias = (const float*)d_in[6];  // [1,256]
    float* out = (float*)d_out;                 // [4096,256] fp32

    float*     hypT = (float*)d_ws;                          // 513*4096*4 = 8.4 MB
    _Float16*  hb   = (_Float16*)((char*)d_ws + HB_OFF);     // 2 MB f16 h
    _Float16*  Bp   = (_Float16*)((char*)d_ws + BP_OFF);     // 67.2 MB

    k_pack    <<<KTILES, 256, 0, stream>>>(W2, b2, Bp);
    k_hypT    <<<129,    512, 0, stream>>>(z, W1, b1, hypT);
    k_hcast   <<<512,    256, 0, stream>>>(h, hb);
    k_init_out<<<4096,   256, 0, stream>>>(bias, out);
    k_gemm    <<<256,    512, 0, stream>>>(hb, hypT, Bp, out);
}